// Round 5
// baseline (160.389 us; speedup 1.0000x reference)
//
#include <hip/hip_runtime.h>

// PNNLayer — exact reference semantics:
//   self_feature[n,a,:] = embeds[(32n + a) mod 50000]   (tile/reshape scramble)
//   out[n,k] = b[k] + Σ_a dists[a,n]·M1[a,k] + SBW[(2n)%3125, k]
//   M1[a,k]  = (1/32)·emb[aid[a]]·W1[k,:]
//   SBW[i,k] = (1/32)·(Σ_{j<32} emb[(16i+j)%N])·W2[k,:]   (only 3125 distinct)
// Measured window is dominated by harness re-poison fills (2×256 MB ≈ 86 µs);
// our controllable part is ~12-16 µs. R5: main kernel was LDS-amplification-
// bound (1 n/thread → full M1 re-read per n, ~512 MB LDS traffic ≈ 7.4 µs);
// 8 n/thread amortizes weight reads 8× → ~150 MB ≈ 2.2 µs.

typedef float f32x4 __attribute__((ext_vector_type(4)));

constexpr int N_PTS  = 50000;
constexpr int A_ANCH = 32;
constexpr int D_DIM  = 64;
constexpr int NSB    = 3125;             // distinct self-feature blocks
constexpr int TN     = 128;              // n-rows per block (8 per thread)
constexpr int MAIN_GRID = (N_PTS + TN - 1) / TN;   // 391 (last block: 80 n)
constexpr int XSTR   = 36;               // 32 + 4 pad, rows 16B-aligned
constexpr int PREP_TILE   = 8;
constexpr int PREP_BLOCKS = (NSB + PREP_TILE - 1) / PREP_TILE;   // 391

// ---- prep: blocks 0..390 -> SBW tiles; block 391 -> M1 ----
__global__ __launch_bounds__(256) void prep_kernel(
        const float* __restrict__ embeds,
        const int*   __restrict__ aid,
        const float* __restrict__ W,      // (64,128)
        float*       __restrict__ M1,     // (32,64)
        float*       __restrict__ SBW)    // (3125,64)
{
    const int t = threadIdx.x;

    if (blockIdx.x == PREP_BLOCKS) {
        // M1[a,k] = (1/32) * Σ_d embeds[aid[a],d] * W[k*128 + d]
        for (int idx = t; idx < A_ANCH * D_DIM; idx += 256) {
            int a = idx >> 6, k = idx & 63;
            const float* erow = embeds + (size_t)aid[a] * D_DIM;   // broadcast in-wave
            const float* wrow = W + (size_t)k * 128;
            float s = 0.0f;
#pragma unroll
            for (int d = 0; d < D_DIM; ++d) s += erow[d] * wrow[d];
            M1[idx] = s * (1.0f / 32.0f);
        }
        return;
    }

    __shared__ float w2[64 * 64];          // w2[d*64+k] = W[k*128+64+d]
    __shared__ float sb[PREP_TILE * 64];   // sb[il*64+d]

    {   // stage W2^T; per-instr LDS writes are 64 contiguous floats (conflict-free)
        int k  = t & 63;
        int d0 = (t >> 6) * 16;
        const float* wr = W + (size_t)k * 128 + 64;
#pragma unroll
        for (int q = 0; q < 16; ++q) w2[(d0 + q) * 64 + k] = wr[d0 + q];
    }

    const int i0 = blockIdx.x * PREP_TILE;
    {   // block sums: sb[il,d] = Σ_j embeds[(16(i0+il)+j) % N, d]; rows = 256 B coalesced
        int d = t & 63, il = t >> 6;
        for (; il < PREP_TILE; il += 4) {
            int i = i0 + il;
            if (i >= NSB) break;           // i increases with il -> break safe
            int base = 16 * i;
            float s = 0.0f;
#pragma unroll
            for (int j = 0; j < 32; ++j) {
                int r = base + j;
                if (r >= N_PTS) r -= N_PTS;
                s += embeds[(size_t)r * D_DIM + d];
            }
            sb[il * 64 + d] = s;
        }
    }
    __syncthreads();
    {   // SBW[i,k] = (1/32) Σ_d sb[il,d]*w2[d,k]; sb broadcast, w2 contiguous
        int k = t & 63, il = t >> 6;
        for (; il < PREP_TILE; il += 4) {
            int i = i0 + il;
            if (i >= NSB) break;
            const float* srow = sb + il * 64;
            float s = 0.0f;
#pragma unroll
            for (int d = 0; d < D_DIM; ++d) s += srow[d] * w2[d * 64 + k];
            SBW[(size_t)i * 64 + k] = s * (1.0f / 32.0f);
        }
    }
}

// ---- main: out[n,k] = b[k] + Σ_a dists[a,n]·M1[a,k] + SBW[(2n)%3125, k] ----
// Block = 128-n tile. Thread = 8 n × 4 k (k0 = 4*(t&15); n = n0 + (t>>4) + 16q).
// 8 n/thread amortizes the m1s weight reads: per jj-step 4 weight b128 feed
// 8 xv b128 + 128 FMAs. Weight reads: 64 consecutive floats per 16 lanes,
// 4x broadcast -> 2-way (free). xv reads: 16-lane broadcast (free).
__global__ __launch_bounds__(256, 4) void pnn_main(
        const float* __restrict__ dists,   // (32, N)
        const float* __restrict__ b,       // (64,)
        const float* __restrict__ M1,      // (32,64)
        const float* __restrict__ SBW,     // (3125,64)
        float*       __restrict__ out)     // (N,64)
{
    __shared__ float m1s[A_ANCH * D_DIM];  // 8 KB
    __shared__ float xs[TN * XSTR];        // 18 KB dists tile [nl][a]

    const int t  = threadIdx.x;
    const int n0 = blockIdx.x * TN;

    {   // stage M1: 512 float4, 2/thread, coalesced
        const float4* M4 = (const float4*)M1;
        float4*       s4 = (float4*)m1s;
#pragma unroll
        for (int q = 0; q < 2; ++q) s4[t + 256 * q] = M4[t + 256 * q];
    }
    {   // stage dists: xs[nl*XSTR + a] = dists[a*N + n0+nl]; 4096 vals, 16/thread.
        // Consecutive lanes -> consecutive nl: global coalesced (256 B/wave/instr).
#pragma unroll
        for (int q = 0; q < 16; ++q) {
            int idx = t + 256 * q;
            int a   = idx >> 7;
            int nl  = idx & 127;
            int col = n0 + nl; if (col >= N_PTS) col = N_PTS - 1;   // tail clamp
            xs[nl * XSTR + a] =
                __builtin_nontemporal_load(dists + (size_t)a * N_PTS + col);
        }
    }
    __syncthreads();

    const int lane_k  = t & 15;
    const int nl_base = t >> 4;            // 0..15
    const int k0      = lane_k * 4;
    const float4 bias = *(const float4*)(b + k0);

    float4 acc[8];
#pragma unroll
    for (int q = 0; q < 8; ++q) {
        int n = n0 + nl_base + 16 * q;
        int nc = (n < N_PTS) ? n : (N_PTS - 1);
        int i  = (2 * nc) % NSB;           // magic-mul
        float4 sbw = *(const float4*)(SBW + (size_t)i * D_DIM + k0);  // L2-resident
        acc[q].x = bias.x + sbw.x; acc[q].y = bias.y + sbw.y;
        acc[q].z = bias.z + sbw.z; acc[q].w = bias.w + sbw.w;
    }

#pragma unroll
    for (int jj = 0; jj < A_ANCH; jj += 4) {
        float4 w0 = *(const float4*)(m1s + (jj + 0) * 64 + k0);
        float4 w1 = *(const float4*)(m1s + (jj + 1) * 64 + k0);
        float4 w2 = *(const float4*)(m1s + (jj + 2) * 64 + k0);
        float4 w3 = *(const float4*)(m1s + (jj + 3) * 64 + k0);
#pragma unroll
        for (int q = 0; q < 8; ++q) {
            float4 xv = *(const float4*)(xs + (nl_base + 16 * q) * XSTR + jj);
            acc[q].x += xv.x * w0.x; acc[q].y += xv.x * w0.y; acc[q].z += xv.x * w0.z; acc[q].w += xv.x * w0.w;
            acc[q].x += xv.y * w1.x; acc[q].y += xv.y * w1.y; acc[q].z += xv.y * w1.z; acc[q].w += xv.y * w1.w;
            acc[q].x += xv.z * w2.x; acc[q].y += xv.z * w2.y; acc[q].z += xv.z * w2.z; acc[q].w += xv.z * w2.w;
            acc[q].x += xv.w * w3.x; acc[q].y += xv.w * w3.y; acc[q].z += xv.w * w3.z; acc[q].w += xv.w * w3.w;
        }
    }

#pragma unroll
    for (int q = 0; q < 8; ++q) {
        int n = n0 + nl_base + 16 * q;
        if (n < N_PTS) {
            f32x4 av; av.x = acc[q].x; av.y = acc[q].y; av.z = acc[q].z; av.w = acc[q].w;
            __builtin_nontemporal_store(av, (f32x4*)(out + (size_t)n * D_DIM + k0));
        }
    }
}

extern "C" void kernel_launch(void* const* d_in, const int* in_sizes, int n_in,
                              void* d_out, int out_size, void* d_ws, size_t ws_size,
                              hipStream_t stream) {
    const float* embeds = (const float*)d_in[0];   // (N, 64)
    const float* dists  = (const float*)d_in[1];   // (32, N)
    const int*   aid    = (const int*)  d_in[2];   // (32,)
    const float* W      = (const float*)d_in[3];   // (64, 128)
    const float* b      = (const float*)d_in[4];   // (64,)
    float*       out    = (float*)d_out;

    float* M1  = (float*)d_ws;                     // 2048 floats (8 KB)
    float* SBW = (float*)d_ws + A_ANCH * D_DIM;    // 3125*64 floats (800 KB)

    prep_kernel<<<PREP_BLOCKS + 1, 256, 0, stream>>>(embeds, aid, W, M1, SBW);
    pnn_main<<<MAIN_GRID, 256, 0, stream>>>(dists, b, M1, SBW, out);
}

// Round 6
// 131.212 us; speedup vs baseline: 1.2224x; 1.2224x over previous
//
#include <hip/hip_runtime.h>

// PNNLayer — exact reference semantics:
//   self_feature[n,a,:] = embeds[(32n + a) mod 50000]   (tile/reshape scramble)
//   out[n,k] = b[k] + Σ_a dists[a,n]·M1[a,k] + SBW[(2n)%3125, k]
//   M1[a,k]  = (1/32)·emb[aid[a]]·W1[k,:]
//   SBW[i,k] = (1/32)·(Σ_{j<32} emb[(16i+j)%N])·W2[k,:]   (only 3125 distinct)
// Window is dominated by harness re-poison fills (2×256 MB ≈ 86 µs).
// R5 lesson: __launch_bounds__(256,4) capped VGPR at 64 → acc[8] spilled to
// scratch (113 MB fetch + 126 MB write of spill traffic, VALUBusy 3%).
// R6: cap at (256,2) → 128 VGPRs, no spill, keep 8 n/thread amortization.

typedef float f32x4 __attribute__((ext_vector_type(4)));

constexpr int N_PTS  = 50000;
constexpr int A_ANCH = 32;
constexpr int D_DIM  = 64;
constexpr int NSB    = 3125;             // distinct self-feature blocks
constexpr int TN     = 128;              // n-rows per block (8 per thread)
constexpr int MAIN_GRID = (N_PTS + TN - 1) / TN;   // 391 (last block: 80 n)
constexpr int XSTR   = 36;               // 32 + 4 pad, rows 16B-aligned
constexpr int PREP_TILE   = 8;
constexpr int PREP_BLOCKS = (NSB + PREP_TILE - 1) / PREP_TILE;   // 391

// ---- prep: blocks 0..390 -> SBW tiles; block 391 -> M1 ----
__global__ __launch_bounds__(256) void prep_kernel(
        const float* __restrict__ embeds,
        const int*   __restrict__ aid,
        const float* __restrict__ W,      // (64,128)
        float*       __restrict__ M1,     // (32,64)
        float*       __restrict__ SBW)    // (3125,64)
{
    const int t = threadIdx.x;

    if (blockIdx.x == PREP_BLOCKS) {
        // M1[a,k] = (1/32) * Σ_d embeds[aid[a],d] * W[k*128 + d]
        for (int idx = t; idx < A_ANCH * D_DIM; idx += 256) {
            int a = idx >> 6, k = idx & 63;
            const float* erow = embeds + (size_t)aid[a] * D_DIM;   // broadcast in-wave
            const float* wrow = W + (size_t)k * 128;
            float s = 0.0f;
#pragma unroll
            for (int d = 0; d < D_DIM; ++d) s += erow[d] * wrow[d];
            M1[idx] = s * (1.0f / 32.0f);
        }
        return;
    }

    __shared__ float w2[64 * 64];          // w2[d*64+k] = W[k*128+64+d]
    __shared__ float sb[PREP_TILE * 64];   // sb[il*64+d]

    {   // stage W2^T; per-instr LDS writes are 64 contiguous floats (conflict-free)
        int k  = t & 63;
        int d0 = (t >> 6) * 16;
        const float* wr = W + (size_t)k * 128 + 64;
#pragma unroll
        for (int q = 0; q < 16; ++q) w2[(d0 + q) * 64 + k] = wr[d0 + q];
    }

    const int i0 = blockIdx.x * PREP_TILE;
    {   // block sums: sb[il,d] = Σ_j embeds[(16(i0+il)+j) % N, d]; rows = 256 B coalesced
        int d = t & 63, il = t >> 6;
        for (; il < PREP_TILE; il += 4) {
            int i = i0 + il;
            if (i >= NSB) break;           // i increases with il -> break safe
            int base = 16 * i;
            float s = 0.0f;
#pragma unroll
            for (int j = 0; j < 32; ++j) {
                int r = base + j;
                if (r >= N_PTS) r -= N_PTS;
                s += embeds[(size_t)r * D_DIM + d];
            }
            sb[il * 64 + d] = s;
        }
    }
    __syncthreads();
    {   // SBW[i,k] = (1/32) Σ_d sb[il,d]*w2[d,k]; sb broadcast, w2 contiguous
        int k = t & 63, il = t >> 6;
        for (; il < PREP_TILE; il += 4) {
            int i = i0 + il;
            if (i >= NSB) break;
            const float* srow = sb + il * 64;
            float s = 0.0f;
#pragma unroll
            for (int d = 0; d < D_DIM; ++d) s += srow[d] * w2[d * 64 + k];
            SBW[(size_t)i * 64 + k] = s * (1.0f / 32.0f);
        }
    }
}

// ---- main: out[n,k] = b[k] + Σ_a dists[a,n]·M1[a,k] + SBW[(2n)%3125, k] ----
// Block = 128-n tile. Thread = 8 n × 4 k (k0 = 4*(t&15); n = n0 + (t>>4) + 16q).
// 8 n/thread amortizes the m1s weight reads 8×. Weight reads: 16 lanes cover
// one 64-float row, 4x duplicated -> broadcast/2-way (free). xv reads: 16-lane
// broadcast (free). __launch_bounds__(256,2): 128-VGPR cap — acc[8]+weights
// ≈ 100 VGPRs live; the (256,4)/64-cap variant SPILLED (R5: 240 MB scratch).
__global__ __launch_bounds__(256, 2) void pnn_main(
        const float* __restrict__ dists,   // (32, N)
        const float* __restrict__ b,       // (64,)
        const float* __restrict__ M1,      // (32,64)
        const float* __restrict__ SBW,     // (3125,64)
        float*       __restrict__ out)     // (N,64)
{
    __shared__ float m1s[A_ANCH * D_DIM];  // 8 KB
    __shared__ float xs[TN * XSTR];        // 18 KB dists tile [nl][a]

    const int t  = threadIdx.x;
    const int n0 = blockIdx.x * TN;

    {   // stage M1: 512 float4, 2/thread, coalesced
        const float4* M4 = (const float4*)M1;
        float4*       s4 = (float4*)m1s;
#pragma unroll
        for (int q = 0; q < 2; ++q) s4[t + 256 * q] = M4[t + 256 * q];
    }
    {   // stage dists: xs[nl*XSTR + a] = dists[a*N + n0+nl]; 4096 vals, 16/thread.
        // Consecutive lanes -> consecutive nl: global coalesced (256 B/wave/instr).
#pragma unroll
        for (int q = 0; q < 16; ++q) {
            int idx = t + 256 * q;
            int a   = idx >> 7;
            int nl  = idx & 127;
            int col = n0 + nl; if (col >= N_PTS) col = N_PTS - 1;   // tail clamp
            xs[nl * XSTR + a] =
                __builtin_nontemporal_load(dists + (size_t)a * N_PTS + col);
        }
    }
    __syncthreads();

    const int lane_k  = t & 15;
    const int nl_base = t >> 4;            // 0..15
    const int k0      = lane_k * 4;
    const float4 bias = *(const float4*)(b + k0);

    float4 acc[8];
#pragma unroll
    for (int q = 0; q < 8; ++q) {
        int n = n0 + nl_base + 16 * q;
        int nc = (n < N_PTS) ? n : (N_PTS - 1);
        int i  = (2 * nc) % NSB;           // magic-mul
        float4 sbw = *(const float4*)(SBW + (size_t)i * D_DIM + k0);  // L2-resident
        acc[q].x = bias.x + sbw.x; acc[q].y = bias.y + sbw.y;
        acc[q].z = bias.z + sbw.z; acc[q].w = bias.w + sbw.w;
    }

#pragma unroll
    for (int jj = 0; jj < A_ANCH; jj += 4) {
        float4 w0 = *(const float4*)(m1s + (jj + 0) * 64 + k0);
        float4 w1 = *(const float4*)(m1s + (jj + 1) * 64 + k0);
        float4 w2 = *(const float4*)(m1s + (jj + 2) * 64 + k0);
        float4 w3 = *(const float4*)(m1s + (jj + 3) * 64 + k0);
#pragma unroll
        for (int q = 0; q < 8; ++q) {
            float4 xv = *(const float4*)(xs + (nl_base + 16 * q) * XSTR + jj);
            acc[q].x += xv.x * w0.x; acc[q].y += xv.x * w0.y; acc[q].z += xv.x * w0.z; acc[q].w += xv.x * w0.w;
            acc[q].x += xv.y * w1.x; acc[q].y += xv.y * w1.y; acc[q].z += xv.y * w1.z; acc[q].w += xv.y * w1.w;
            acc[q].x += xv.z * w2.x; acc[q].y += xv.z * w2.y; acc[q].z += xv.z * w2.z; acc[q].w += xv.z * w2.w;
            acc[q].x += xv.w * w3.x; acc[q].y += xv.w * w3.y; acc[q].z += xv.w * w3.z; acc[q].w += xv.w * w3.w;
        }
    }

#pragma unroll
    for (int q = 0; q < 8; ++q) {
        int n = n0 + nl_base + 16 * q;
        if (n < N_PTS) {
            f32x4 av; av.x = acc[q].x; av.y = acc[q].y; av.z = acc[q].z; av.w = acc[q].w;
            __builtin_nontemporal_store(av, (f32x4*)(out + (size_t)n * D_DIM + k0));
        }
    }
}

extern "C" void kernel_launch(void* const* d_in, const int* in_sizes, int n_in,
                              void* d_out, int out_size, void* d_ws, size_t ws_size,
                              hipStream_t stream) {
    const float* embeds = (const float*)d_in[0];   // (N, 64)
    const float* dists  = (const float*)d_in[1];   // (32, N)
    const int*   aid    = (const int*)  d_in[2];   // (32,)
    const float* W      = (const float*)d_in[3];   // (64, 128)
    const float* b      = (const float*)d_in[4];   // (64,)
    float*       out    = (float*)d_out;

    float* M1  = (float*)d_ws;                     // 2048 floats (8 KB)
    float* SBW = (float*)d_ws + A_ANCH * D_DIM;    // 3125*64 floats (800 KB)

    prep_kernel<<<PREP_BLOCKS + 1, 256, 0, stream>>>(embeds, aid, W, M1, SBW);
    pnn_main<<<MAIN_GRID, 256, 0, stream>>>(dists, b, M1, SBW, out);
}

// Round 7
// 99.326 us; speedup vs baseline: 1.6148x; 1.3210x over previous
//
#include <hip/hip_runtime.h>

// PNNLayer — exact reference semantics:
//   self_feature[n,a,:] = embeds[(32n + a) mod 50000]   (tile/reshape scramble)
//   out[n,k] = b[k] + Σ_a dists[a,n]·M1[a,k] + SBW[(2n)%3125, k]
//   M1[a,k]  = (1/32)·emb[aid[a]]·W1[k,:]
//   SBW[i,k] = (1/32)·(Σ_{j<32} emb[(16i+j)%N])·W2[k,:]   (only 3125 distinct)
// Window is dominated by harness re-poison fills (2×256 MB ≈ 86 µs).
// R5: launch_bounds(256,4) → 64-VGPR cap → acc[8] spilled (240 MB scratch).
// R6: cap 128 still spilled ~130 MB — the FULLY-UNROLLED jj×q nest let the
//     scheduler hoist ~96 ds_read_b128, ballooning live range past 128.
// R7: #pragma unroll 1 on jj → live set ≈ 90 VGPRs, no spill; inner loop is
//     VALU-bound (128 FMA ≈ 256 cyc vs 12 ds_read_b128 ≈ 144 cyc).

typedef float f32x4 __attribute__((ext_vector_type(4)));

constexpr int N_PTS  = 50000;
constexpr int A_ANCH = 32;
constexpr int D_DIM  = 64;
constexpr int NSB    = 3125;             // distinct self-feature blocks
constexpr int TN     = 128;              // n-rows per block (8 per thread)
constexpr int MAIN_GRID = (N_PTS + TN - 1) / TN;   // 391 (last block: 80 n)
constexpr int XSTR   = 36;               // 32 + 4 pad, rows 16B-aligned
constexpr int PREP_TILE   = 8;
constexpr int PREP_BLOCKS = (NSB + PREP_TILE - 1) / PREP_TILE;   // 391

// ---- prep: blocks 0..390 -> SBW tiles; block 391 -> M1 ----
__global__ __launch_bounds__(256) void prep_kernel(
        const float* __restrict__ embeds,
        const int*   __restrict__ aid,
        const float* __restrict__ W,      // (64,128)
        float*       __restrict__ M1,     // (32,64)
        float*       __restrict__ SBW)    // (3125,64)
{
    const int t = threadIdx.x;

    if (blockIdx.x == PREP_BLOCKS) {
        // M1[a,k] = (1/32) * Σ_d embeds[aid[a],d] * W[k*128 + d]
        for (int idx = t; idx < A_ANCH * D_DIM; idx += 256) {
            int a = idx >> 6, k = idx & 63;
            const float* erow = embeds + (size_t)aid[a] * D_DIM;   // broadcast in-wave
            const float* wrow = W + (size_t)k * 128;
            float s = 0.0f;
#pragma unroll
            for (int d = 0; d < D_DIM; ++d) s += erow[d] * wrow[d];
            M1[idx] = s * (1.0f / 32.0f);
        }
        return;
    }

    __shared__ float w2[64 * 64];          // w2[d*64+k] = W[k*128+64+d]
    __shared__ float sb[PREP_TILE * 64];   // sb[il*64+d]

    {   // stage W2^T; per-instr LDS writes are 64 contiguous floats (conflict-free)
        int k  = t & 63;
        int d0 = (t >> 6) * 16;
        const float* wr = W + (size_t)k * 128 + 64;
#pragma unroll
        for (int q = 0; q < 16; ++q) w2[(d0 + q) * 64 + k] = wr[d0 + q];
    }

    const int i0 = blockIdx.x * PREP_TILE;
    {   // block sums: sb[il,d] = Σ_j embeds[(16(i0+il)+j) % N, d]; rows = 256 B coalesced
        int d = t & 63, il = t >> 6;
        for (; il < PREP_TILE; il += 4) {
            int i = i0 + il;
            if (i >= NSB) break;           // i increases with il -> break safe
            int base = 16 * i;
            float s = 0.0f;
#pragma unroll
            for (int j = 0; j < 32; ++j) {
                int r = base + j;
                if (r >= N_PTS) r -= N_PTS;
                s += embeds[(size_t)r * D_DIM + d];
            }
            sb[il * 64 + d] = s;
        }
    }
    __syncthreads();
    {   // SBW[i,k] = (1/32) Σ_d sb[il,d]*w2[d,k]; sb broadcast, w2 contiguous
        int k = t & 63, il = t >> 6;
        for (; il < PREP_TILE; il += 4) {
            int i = i0 + il;
            if (i >= NSB) break;
            const float* srow = sb + il * 64;
            float s = 0.0f;
#pragma unroll
            for (int d = 0; d < D_DIM; ++d) s += srow[d] * w2[d * 64 + k];
            SBW[(size_t)i * 64 + k] = s * (1.0f / 32.0f);
        }
    }
}

// ---- main: out[n,k] = b[k] + Σ_a dists[a,n]·M1[a,k] + SBW[(2n)%3125, k] ----
// Block = 128-n tile. Thread = 8 n × 4 k (k0 = 4*(t&15); n = n0 + (t>>4) + 16q).
// jj loop NOT unrolled (unroll 1): keeps live VGPRs ≈ 90 (acc 32 + weights 16
// + xv 32) — fully-unrolled variants spilled (R5/R6). Weight reads: 16 lanes
// cover one 64-float row, 4x duplicated -> broadcast/2-way (free). xv reads:
// 16-lane broadcast (free).
__global__ __launch_bounds__(256, 2) void pnn_main(
        const float* __restrict__ dists,   // (32, N)
        const float* __restrict__ b,       // (64,)
        const float* __restrict__ M1,      // (32,64)
        const float* __restrict__ SBW,     // (3125,64)
        float*       __restrict__ out)     // (N,64)
{
    __shared__ float m1s[A_ANCH * D_DIM];  // 8 KB
    __shared__ float xs[TN * XSTR];        // 18 KB dists tile [nl][a]

    const int t  = threadIdx.x;
    const int n0 = blockIdx.x * TN;

    {   // stage M1: 512 float4, 2/thread, coalesced
        const float4* M4 = (const float4*)M1;
        float4*       s4 = (float4*)m1s;
#pragma unroll
        for (int q = 0; q < 2; ++q) s4[t + 256 * q] = M4[t + 256 * q];
    }
    {   // stage dists: xs[nl*XSTR + a] = dists[a*N + n0+nl]; 4096 vals, 16/thread.
        // Consecutive lanes -> consecutive nl: global coalesced (256 B/wave/instr).
#pragma unroll
        for (int q = 0; q < 16; ++q) {
            int idx = t + 256 * q;
            int a   = idx >> 7;
            int nl  = idx & 127;
            int col = n0 + nl; if (col >= N_PTS) col = N_PTS - 1;   // tail clamp
            xs[nl * XSTR + a] =
                __builtin_nontemporal_load(dists + (size_t)a * N_PTS + col);
        }
    }
    __syncthreads();

    const int lane_k  = t & 15;
    const int nl_base = t >> 4;            // 0..15
    const int k0      = lane_k * 4;
    const float4 bias = *(const float4*)(b + k0);

    float4 acc[8];
#pragma unroll
    for (int q = 0; q < 8; ++q) {
        int n = n0 + nl_base + 16 * q;
        int nc = (n < N_PTS) ? n : (N_PTS - 1);
        int i  = (2 * nc) % NSB;           // magic-mul
        float4 sbw = *(const float4*)(SBW + (size_t)i * D_DIM + k0);  // L2-resident
        acc[q].x = bias.x + sbw.x; acc[q].y = bias.y + sbw.y;
        acc[q].z = bias.z + sbw.z; acc[q].w = bias.w + sbw.w;
    }

#pragma unroll 1   // DO NOT fully unroll: reg-pressure balloon -> spills (R5/R6)
    for (int jj = 0; jj < A_ANCH; jj += 4) {
        float4 w0 = *(const float4*)(m1s + (jj + 0) * 64 + k0);
        float4 w1 = *(const float4*)(m1s + (jj + 1) * 64 + k0);
        float4 w2 = *(const float4*)(m1s + (jj + 2) * 64 + k0);
        float4 w3 = *(const float4*)(m1s + (jj + 3) * 64 + k0);
#pragma unroll
        for (int q = 0; q < 8; ++q) {
            float4 xv = *(const float4*)(xs + (nl_base + 16 * q) * XSTR + jj);
            acc[q].x += xv.x * w0.x; acc[q].y += xv.x * w0.y; acc[q].z += xv.x * w0.z; acc[q].w += xv.x * w0.w;
            acc[q].x += xv.y * w1.x; acc[q].y += xv.y * w1.y; acc[q].z += xv.y * w1.z; acc[q].w += xv.y * w1.w;
            acc[q].x += xv.z * w2.x; acc[q].y += xv.z * w2.y; acc[q].z += xv.z * w2.z; acc[q].w += xv.z * w2.w;
            acc[q].x += xv.w * w3.x; acc[q].y += xv.w * w3.y; acc[q].z += xv.w * w3.z; acc[q].w += xv.w * w3.w;
        }
    }

#pragma unroll
    for (int q = 0; q < 8; ++q) {
        int n = n0 + nl_base + 16 * q;
        if (n < N_PTS) {
            f32x4 av; av.x = acc[q].x; av.y = acc[q].y; av.z = acc[q].z; av.w = acc[q].w;
            __builtin_nontemporal_store(av, (f32x4*)(out + (size_t)n * D_DIM + k0));
        }
    }
}

extern "C" void kernel_launch(void* const* d_in, const int* in_sizes, int n_in,
                              void* d_out, int out_size, void* d_ws, size_t ws_size,
                              hipStream_t stream) {
    const float* embeds = (const float*)d_in[0];   // (N, 64)
    const float* dists  = (const float*)d_in[1];   // (32, N)
    const int*   aid    = (const int*)  d_in[2];   // (32,)
    const float* W      = (const float*)d_in[3];   // (64, 128)
    const float* b      = (const float*)d_in[4];   // (64,)
    float*       out    = (float*)d_out;

    float* M1  = (float*)d_ws;                     // 2048 floats (8 KB)
    float* SBW = (float*)d_ws + A_ANCH * D_DIM;    // 3125*64 floats (800 KB)

    prep_kernel<<<PREP_BLOCKS + 1, 256, 0, stream>>>(embeds, aid, W, M1, SBW);
    pnn_main<<<MAIN_GRID, 256, 0, stream>>>(dists, b, M1, SBW, out);
}